// Round 18
// baseline (184.355 us; speedup 1.0000x reference)
//
#include <hip/hip_runtime.h>

typedef __bf16 bf16_t;
typedef __bf16 bf16x4 __attribute__((ext_vector_type(4)));
typedef __bf16 bf16x8 __attribute__((ext_vector_type(8)));
typedef float  f32x4  __attribute__((ext_vector_type(4)));
typedef float  f32x16 __attribute__((ext_vector_type(16)));
typedef unsigned int u32;

#define MFMA16(a, b, c) __builtin_amdgcn_mfma_f32_16x16x32_bf16((a), (b), (c), 0, 0, 0)
#define MFMA32(a, b, c) __builtin_amdgcn_mfma_f32_32x32x16_bf16((a), (b), (c), 0, 0, 0)

__device__ __forceinline__ void gld_lds16(const bf16_t* g, bf16_t* l) {
  __builtin_amdgcn_global_load_lds((__attribute__((address_space(1))) void*)g,
                                   (__attribute__((address_space(3))) void*)l, 16, 0, 0);
}
__device__ __forceinline__ u32 cvt_pk_bf16(float lo, float hi) {
  u32 r;
  asm("v_cvt_pk_bf16_f32 %0, %1, %2" : "=v"(r) : "v"(lo), "v"(hi));
  return r;
}

// ---------------- prep: x cast (big) ----------------
__global__ void cast_f32_bf16(const float* __restrict__ s, bf16_t* __restrict__ d, int n) {
  int i = (blockIdx.x * blockDim.x + threadIdx.x) * 4;
  if (i >= n) return;
  float4 v = *(const float4*)(s + i);
  bf16x4 o;
  o[0] = (bf16_t)v.x; o[1] = (bf16_t)v.y; o[2] = (bf16_t)v.z; o[3] = (bf16_t)v.w;
  *(bf16x4*)(d + i) = o;
}

// ---------------- prep: all weight casts + bias concat in one launch ----------------
__global__ void prep_w(const float* __restrict__ Wq, const float* __restrict__ Wk,
                       const float* __restrict__ Wv, const float* __restrict__ Wo,
                       const float* __restrict__ bq, const float* __restrict__ bk,
                       const float* __restrict__ bv,
                       bf16_t* __restrict__ wqkv, bf16_t* __restrict__ wob,
                       float* __restrict__ qkvb) {
  const int NW = 768 * 768;
  const int t = blockIdx.x * 256 + threadIdx.x;
  const int i = t * 4;
  if (i < 3 * NW) {
    const float* s; int off;
    if (i < NW)          { s = Wq; off = i; }
    else if (i < 2 * NW) { s = Wk; off = i - NW; }
    else                 { s = Wv; off = i - 2 * NW; }
    float4 v = *(const float4*)(s + off);
    bf16x4 o;
    o[0] = (bf16_t)v.x; o[1] = (bf16_t)v.y; o[2] = (bf16_t)v.z; o[3] = (bf16_t)v.w;
    *(bf16x4*)(wqkv + i) = o;
  } else if (i < 4 * NW) {
    const int off = i - 3 * NW;
    float4 v = *(const float4*)(Wo + off);
    bf16x4 o;
    o[0] = (bf16_t)v.x; o[1] = (bf16_t)v.y; o[2] = (bf16_t)v.z; o[3] = (bf16_t)v.w;
    *(bf16x4*)(wob + off) = o;
  }
  if (t < 2304) qkvb[t] = t < 768 ? bq[t] : (t < 1536 ? bk[t - 768] : bv[t - 1536]);
}

// ---------------- fused QKV GEMM (R17-verified): region branch hoisted outside K-loop ----------------
__global__ __launch_bounds__(256) void gemm_qkv(
    const bf16_t* __restrict__ A, const bf16_t* __restrict__ B,
    const float* __restrict__ bias,
    bf16_t* __restrict__ qb, bf16_t* __restrict__ kb2, bf16_t* __restrict__ vtb) {
  __shared__ __align__(16) bf16_t As[128 * 64];
  __shared__ __align__(16) bf16_t Bs[128 * 64];
  const int K = 768;
  const int p = blockIdx.x;
  const int xcd = p & 7, u = p >> 3;           // u in 0..143
  const int bm = xcd * 8 + u / 18;             // 8 bm rows per XCD
  const int bn = u - (u / 18) * 18;            // bn fastest within a bm
  const int tid = threadIdx.x;
  const int w = tid >> 6, l = tid & 63, lg = l >> 4, ln = l & 15;
  const int wr = w >> 1, wc = w & 1;
  const int lr8 = l >> 3, lc8 = l & 7;
  const int region = (bn * 128) / 768;
  const int ln7 = ln & 7;
  f32x4 acc[4][4] = {};
  if (region != 2) {  // ---- q/k path: normal operand order ----
    for (int kb = 0; kb < K / 64; ++kb) {
      const int k0 = kb * 64;
#pragma unroll
      for (int i = 0; i < 4; ++i) {
        const int row = w * 32 + i * 8 + lr8;
        const int so = k0 + ((lc8 ^ (row & 7)) << 3);
        gld_lds16(A + (size_t)(bm * 128 + row) * K + so, As + (w * 32 + i * 8) * 64 + l * 8);
        gld_lds16(B + (size_t)(bn * 128 + row) * K + so, Bs + (w * 32 + i * 8) * 64 + l * 8);
      }
      __syncthreads();
#pragma unroll
      for (int kk = 0; kk < 2; ++kk) {
        bf16x8 af[4], bfr[4];
#pragma unroll
        for (int m = 0; m < 4; ++m) {
          const int jc = ((kk * 4 + lg) ^ ln7) << 3;
          af[m]  = *(const bf16x8*)(As + (wr * 64 + m * 16 + ln) * 64 + jc);
          bfr[m] = *(const bf16x8*)(Bs + (wc * 64 + m * 16 + ln) * 64 + jc);
        }
#pragma unroll
        for (int m = 0; m < 4; ++m)
#pragma unroll
          for (int n = 0; n < 4; ++n) acc[m][n] = MFMA16(af[m], bfr[n], acc[m][n]);
      }
      __syncthreads();
    }
    const float scl = (region == 0) ? 0.18033688011112042f : 1.0f;  // 0.125*log2(e)
    bf16_t* dst = region == 0 ? qb : kb2;
#pragma unroll
    for (int m = 0; m < 4; ++m)
#pragma unroll
      for (int n = 0; n < 4; ++n)
#pragma unroll
        for (int j = 0; j < 4; ++j) {
          const int gm = bm * 128 + wr * 64 + m * 16 + lg * 4 + j;   // t
          const int gn = bn * 128 + wc * 64 + n * 16 + ln;           // qkv col
          const float v = (acc[m][n][j] + bias[gn]) * scl;
          const int c = gn - region * 768;
          const int bb = gm >> 12, tt = gm & 4095;
          const int hh = c >> 6, d = c & 63;
          dst[((size_t)(bb * 12 + hh) * 4096 + tt) * 64 + d] = (bf16_t)v;
        }
  } else {  // ---- v path: C^T (swapped operands) for coalesced [B,H,D,T] writes ----
    for (int kb = 0; kb < K / 64; ++kb) {
      const int k0 = kb * 64;
#pragma unroll
      for (int i = 0; i < 4; ++i) {
        const int row = w * 32 + i * 8 + lr8;
        const int so = k0 + ((lc8 ^ (row & 7)) << 3);
        gld_lds16(A + (size_t)(bm * 128 + row) * K + so, As + (w * 32 + i * 8) * 64 + l * 8);
        gld_lds16(B + (size_t)(bn * 128 + row) * K + so, Bs + (w * 32 + i * 8) * 64 + l * 8);
      }
      __syncthreads();
#pragma unroll
      for (int kk = 0; kk < 2; ++kk) {
        bf16x8 af[4], bfr[4];
#pragma unroll
        for (int m = 0; m < 4; ++m) {
          const int jc = ((kk * 4 + lg) ^ ln7) << 3;
          af[m]  = *(const bf16x8*)(As + (wr * 64 + m * 16 + ln) * 64 + jc);
          bfr[m] = *(const bf16x8*)(Bs + (wc * 64 + m * 16 + ln) * 64 + jc);
        }
#pragma unroll
        for (int m = 0; m < 4; ++m)
#pragma unroll
          for (int n = 0; n < 4; ++n) acc[m][n] = MFMA16(bfr[n], af[m], acc[m][n]);
      }
      __syncthreads();
    }
#pragma unroll
    for (int m = 0; m < 4; ++m)
#pragma unroll
      for (int n = 0; n < 4; ++n)
#pragma unroll
        for (int j = 0; j < 4; ++j) {
          const int gn = bn * 128 + wc * 64 + n * 16 + lg * 4 + j;   // qkv col (channel)
          const int gm = bm * 128 + wr * 64 + m * 16 + ln;           // t
          const float v = acc[m][n][j] + bias[gn];
          const int c = gn - 1536;
          const int bb = gm >> 12, tt = gm & 4095;
          const int hh = c >> 6, d = c & 63;
          vtb[((size_t)(bb * 12 + hh) * 64 + d) * 4096 + tt] = (bf16_t)v;
        }
  }
}

// ---------------- flash attention (causal): 64-row qtiles, 4 waves, fine-grained balance ----------------
// 1536 blocks (head hb, 64-row qtile q64, heavy-first) x 256 thr = 4 waves (wq x wc).
// All waves process tile t per step; wave wc handles k-rows [32wc,32wc+32). Same verified
// per-wave body as R15; LDS 32KB dbuf -> 4 blocks resident + 2 queued per CU: greedy
// scheduling smooths the causal imbalance (R17: static 3 blocks/CU, per-CU spread 68..130
// steps -> occupancy 35%). Staging: 256 thr x 2 chunks x {K,V} = 512 chunks/tile (full).
__global__ __launch_bounds__(256) void attn_fwd(
    const bf16_t* __restrict__ q, const bf16_t* __restrict__ k,
    const bf16_t* __restrict__ vt, bf16_t* __restrict__ y) {
  __shared__ __align__(16) unsigned char SMEM[33280];
  bf16_t* Ks = (bf16_t*)SMEM;            // [dbuf][4096] (8KB per buf)
  bf16_t* Vs = (bf16_t*)(SMEM + 16384);  // [dbuf][4096]
  float*  osh = (float*)SMEM;            // combine: [2][32][64] f32 (16KB)
  float*  lsh = (float*)(SMEM + 32768);  // combine: [2][32] f32 row sums

  const int p = blockIdx.x;
  const int xcd = p & 7, slot = p >> 3;        // 192 slots per XCD
  const int hb = xcd + 8 * (slot % 3);         // 3 heads per XCD (L2-resident K/V)
  const int q64 = 63 - slot / 3;               // heavy-first
  const int tid = threadIdx.x;
  const int w = tid >> 6, l = tid & 63, lq = l & 31, lh = l >> 5;
  const int wq = w >> 1, wc = w & 1;
  const size_t hbo = (size_t)hb * (4096 * 64);
  const bf16_t* qh = q + hbo;
  const bf16_t* kh = k + hbo;
  const bf16_t* vh = vt + hbo;

  const int q0 = q64 * 64 + wq * 32;           // wave's first q row
  const int qidx = q0 + lq;                    // this lane's q row
  const int nst = q64 + 1;                     // tiles to sweep

  // staging: thread covers chunks {tid, tid+256} of K and of V (4 gld_lds/step)
  const int sr0 = tid & 31;
  const int sc0 = ((((tid >> 6) & 3) << 1) | ((tid >> 5) & 1)) << 3;
  const bf16_t* kA = kh + ((size_t)sr0 * 64 + sc0);
  const bf16_t* kB = kh + ((size_t)(sr0 + 32) * 64 + sc0);
  const bf16_t* vA = vh + ((size_t)sr0 * 4096 + sc0);
  const bf16_t* vB = vh + ((size_t)(sr0 + 32) * 4096 + sc0);

  bf16x8 qf[4];
#pragma unroll
  for (int ds = 0; ds < 4; ++ds)
    qf[ds] = *(const bf16x8*)(qh + (size_t)qidx * 64 + 16 * ds + 8 * lh);
  bf16x8 ones;
#pragma unroll
  for (int j = 0; j < 8; ++j) ones[j] = (bf16_t)1.0f;

  gld_lds16(kA, Ks + tid * 8);
  gld_lds16(kB, Ks + 2048 + tid * 8);
  gld_lds16(vA, Vs + tid * 8);
  gld_lds16(vB, Vs + 2048 + tid * 8);
  __syncthreads();

  f32x16 o0 = {}, o1 = {}, osum = {};

  int cur = 0;
  for (int t = 0; t < nst; ++t) {
    if (t + 1 < nst) {  // prefetch next tile into other buffer
      bf16_t* kd = Ks + (cur ^ 1) * 4096;
      bf16_t* vd = Vs + (cur ^ 1) * 4096;
      gld_lds16(kA + 4096, kd + tid * 8);
      gld_lds16(kB + 4096, kd + 2048 + tid * 8);
      gld_lds16(vA + 64, vd + tid * 8);
      gld_lds16(vB + 64, vd + 2048 + tid * 8);
    }
    kA += 4096; kB += 4096; vA += 64; vB += 64;
    const int kvb = t * 64;
    if (kvb <= q0 + 31) {  // causal: this wave still needs this tile
      const bool diag = (kvb + 63 > q0);
      const bf16_t* KsW = Ks + cur * 4096;
      const bf16_t* VsW = Vs + cur * 4096;
      f32x16 st = {};
      __builtin_amdgcn_s_setprio(1);
#pragma unroll
      for (int ds = 0; ds < 4; ++ds) {
        bf16x8 kf = *(const bf16x8*)(KsW + (wc * 4 + ds) * 512 + l * 8);
        st = MFMA32(kf, qf[ds], st);
      }
      __builtin_amdgcn_s_setprio(0);
      float pv[16];
#pragma unroll
      for (int r = 0; r < 16; ++r) pv[r] = __builtin_amdgcn_exp2f(st[r]);
      if (diag) {
        const int kb0 = kvb + wc * 32 + 4 * lh;
#pragma unroll
        for (int r = 0; r < 16; ++r)
          if (kb0 + (r & 3) + 8 * (r >> 2) > qidx) pv[r] = 0.f;
      }
      u32 pq[8];
#pragma unroll
      for (int g = 0; g < 8; ++g) pq[g] = cvt_pk_bf16(pv[2 * g], pv[2 * g + 1]);
#pragma unroll
      for (int ks2 = 0; ks2 < 2; ++ks2) {
        asm("v_permlane32_swap_b32 %0, %1" : "+v"(pq[4 * ks2 + 0]), "+v"(pq[4 * ks2 + 2]));
        asm("v_permlane32_swap_b32 %0, %1" : "+v"(pq[4 * ks2 + 1]), "+v"(pq[4 * ks2 + 3]));
      }
      __builtin_amdgcn_s_setprio(1);
#pragma unroll
      for (int ks = 0; ks < 2; ++ks) {
        bf16x8 pa = *(const bf16x8*)&pq[ks * 4];
        bf16x8 v0 = *(const bf16x8*)(VsW + (2 * wc + ks) * 512 + l * 8);
        bf16x8 v1 = *(const bf16x8*)(VsW + (4 + 2 * wc + ks) * 512 + l * 8);
        o0 = MFMA32(pa, v0, o0);
        o1 = MFMA32(pa, v1, o1);
        osum = MFMA32(pa, ones, osum);   // row-sums of P on the MFMA pipe
      }
      __builtin_amdgcn_s_setprio(0);
    }
    __syncthreads();
    cur ^= 1;
  }

  // cross-half combine through LDS (staging buffers dead now)
  if (wc == 1) {
#pragma unroll
    for (int r = 0; r < 16; ++r) {
      osh[wq * 2048 + r * 64 + l] = o0[r];
      osh[wq * 2048 + (16 + r) * 64 + l] = o1[r];
    }
    if (lq == 0) {
#pragma unroll
      for (int r = 0; r < 16; ++r)
        lsh[wq * 32 + (r & 3) + 8 * (r >> 2) + 4 * lh] = osum[r];
    }
  }
  __syncthreads();
  if (wc == 0) {
#pragma unroll
    for (int r = 0; r < 16; ++r) {
      o0[r] += osh[wq * 2048 + r * 64 + l];
      o1[r] += osh[wq * 2048 + (16 + r) * 64 + l];
    }
    float linv[16];
#pragma unroll
    for (int r = 0; r < 16; ++r) {
      const int rl = (r & 3) + 8 * (r >> 2) + 4 * lh;
      linv[r] = 1.0f / (osum[r] + lsh[wq * 32 + rl]);
    }
    const int b = hb / 12, h = hb - b * 12;
#pragma unroll
    for (int r = 0; r < 16; ++r) {
      const int row = q0 + (r & 3) + 8 * (r >> 2) + 4 * lh;
      bf16_t* yr = y + ((size_t)b * 4096 + row) * 768 + h * 64 + lq;
      yr[0]  = (bf16_t)(o0[r] * linv[r]);
      yr[32] = (bf16_t)(o1[r] * linv[r]);
    }
  }
}

// ---------------- output GEMM (R17-verified): 64x128 tile, grid 768 = 3/CU ----------------
__global__ __launch_bounds__(256) void gemm_out(
    const bf16_t* __restrict__ A, const bf16_t* __restrict__ B,
    const float* __restrict__ bias, float* __restrict__ out) {
  __shared__ __align__(16) bf16_t As[64 * 64];
  __shared__ __align__(16) bf16_t Bs[128 * 64];
  const int K = 768;
  const int p = blockIdx.x;
  const int xcd = p & 7, u = p >> 3;           // u in 0..95
  const int bm = xcd * 16 + u / 6;             // 16 bm rows per XCD (128 total)
  const int bn = u - (u / 6) * 6;
  const int tid = threadIdx.x;
  const int w = tid >> 6, l = tid & 63, lg = l >> 4, ln = l & 15;
  const int lr8 = l >> 3, lc8 = l & 7;
  const int ln7 = ln & 7;
  f32x4 acc[4][2] = {};
  for (int kb = 0; kb < K / 64; ++kb) {
    const int k0 = kb * 64;
#pragma unroll
    for (int i = 0; i < 2; ++i) {              // A: 64 rows, 2 chunk-passes
      const int row = w * 16 + i * 8 + lr8;
      const int so = k0 + ((lc8 ^ (row & 7)) << 3);
      gld_lds16(A + (size_t)(bm * 64 + row) * K + so, As + (w * 16 + i * 8) * 64 + l * 8);
    }
#pragma unroll
    for (int i = 0; i < 4; ++i) {              // B: 128 rows, 4 chunk-passes
      const int row = w * 32 + i * 8 + lr8;
      const int so = k0 + ((lc8 ^ (row & 7)) << 3);
      gld_lds16(B + (size_t)(bn * 128 + row) * K + so, Bs + (w * 32 + i * 8) * 64 + l * 8);
    }
    __syncthreads();
#pragma unroll
    for (int kk = 0; kk < 2; ++kk) {
      const int jc = ((kk * 4 + lg) ^ ln7) << 3;
      bf16x8 af[4], bfr[2];
#pragma unroll
      for (int m = 0; m < 4; ++m)
        af[m] = *(const bf16x8*)(As + (m * 16 + ln) * 64 + jc);
#pragma unroll
      for (int n = 0; n < 2; ++n)
        bfr[n] = *(const bf16x8*)(Bs + (w * 32 + n * 16 + ln) * 64 + jc);
#pragma unroll
      for (int m = 0; m < 4; ++m)
#pragma unroll
        for (int n = 0; n < 2; ++n) acc[m][n] = MFMA16(af[m], bfr[n], acc[m][n]);
    }
    __syncthreads();
  }
#pragma unroll
  for (int m = 0; m < 4; ++m) {
#pragma unroll
    for (int n = 0; n < 2; ++n) {
#pragma unroll
      for (int j = 0; j < 4; ++j) {
        const int gm = bm * 64 + m * 16 + lg * 4 + j;
        const int gn = bn * 128 + w * 32 + n * 16 + ln;
        out[(size_t)gm * 768 + gn] = acc[m][n][j] + bias[gn];
      }
    }
  }
}

// ---------------- launch ----------------
extern "C" void kernel_launch(void* const* d_in, const int* in_sizes, int n_in,
                              void* d_out, int out_size, void* d_ws, size_t ws_size,
                              hipStream_t stream) {
  const float* x  = (const float*)d_in[0];
  const float* Wq = (const float*)d_in[1];
  const float* bq = (const float*)d_in[2];
  const float* Wk = (const float*)d_in[3];
  const float* bk = (const float*)d_in[4];
  const float* Wv = (const float*)d_in[5];
  const float* bv = (const float*)d_in[6];
  const float* Wo = (const float*)d_in[7];
  const float* bo = (const float*)d_in[8];
  float* out = (float*)d_out;

  const int M = 8192, C = 768, QKV = 2304;
  bf16_t* xb   = (bf16_t*)d_ws;                    // [8192][768]
  bf16_t* wqkv = xb + (size_t)M * C;               // [2304][768]
  bf16_t* wob  = wqkv + (size_t)QKV * C;           // [768][768]
  float*  qkvb = (float*)(wob + (size_t)C * C);    // [2304]
  bf16_t* qbuf = (bf16_t*)(qkvb + QKV);            // [B,H,T,D] (q pre-scaled)
  bf16_t* kbuf = qbuf + (size_t)M * C;             // [B,H,T,D]
  bf16_t* vtb  = kbuf + (size_t)M * C;             // [B,H,D,T]
  bf16_t* yb   = xb;                               // reuse xb (dead after gemm_qkv)

  cast_f32_bf16<<<6144, 256, 0, stream>>>(x, xb, M * C);
  prep_w<<<2304, 256, 0, stream>>>(Wq, Wk, Wv, Wo, bq, bk, bv, wqkv, wob, qkvb);

  gemm_qkv<<<1152, 256, 0, stream>>>(xb, wqkv, qkvb, qbuf, kbuf, vtb);
  attn_fwd<<<1536, 256, 0, stream>>>(qbuf, kbuf, vtb, yb);
  gemm_out<<<768, 256, 0, stream>>>(yb, wob, bo, out);
}

// Round 19
// 156.745 us; speedup vs baseline: 1.1761x; 1.1761x over previous
//
#include <hip/hip_runtime.h>

typedef __bf16 bf16_t;
typedef __bf16 bf16x4 __attribute__((ext_vector_type(4)));
typedef __bf16 bf16x8 __attribute__((ext_vector_type(8)));
typedef float  f32x4  __attribute__((ext_vector_type(4)));
typedef float  f32x16 __attribute__((ext_vector_type(16)));
typedef unsigned int u32;

#define MFMA16(a, b, c) __builtin_amdgcn_mfma_f32_16x16x32_bf16((a), (b), (c), 0, 0, 0)
#define MFMA32(a, b, c) __builtin_amdgcn_mfma_f32_32x32x16_bf16((a), (b), (c), 0, 0, 0)

__device__ __forceinline__ void gld_lds16(const bf16_t* g, bf16_t* l) {
  __builtin_amdgcn_global_load_lds((__attribute__((address_space(1))) void*)g,
                                   (__attribute__((address_space(3))) void*)l, 16, 0, 0);
}
__device__ __forceinline__ u32 cvt_pk_bf16(float lo, float hi) {
  u32 r;
  asm("v_cvt_pk_bf16_f32 %0, %1, %2" : "=v"(r) : "v"(lo), "v"(hi));
  return r;
}

// ---------------- prep: x cast (big) ----------------
__global__ void cast_f32_bf16(const float* __restrict__ s, bf16_t* __restrict__ d, int n) {
  int i = (blockIdx.x * blockDim.x + threadIdx.x) * 4;
  if (i >= n) return;
  float4 v = *(const float4*)(s + i);
  bf16x4 o;
  o[0] = (bf16_t)v.x; o[1] = (bf16_t)v.y; o[2] = (bf16_t)v.z; o[3] = (bf16_t)v.w;
  *(bf16x4*)(d + i) = o;
}

// ---------------- prep: all weight casts + bias concat in one launch ----------------
__global__ void prep_w(const float* __restrict__ Wq, const float* __restrict__ Wk,
                       const float* __restrict__ Wv, const float* __restrict__ Wo,
                       const float* __restrict__ bq, const float* __restrict__ bk,
                       const float* __restrict__ bv,
                       bf16_t* __restrict__ wqkv, bf16_t* __restrict__ wob,
                       float* __restrict__ qkvb) {
  const int NW = 768 * 768;
  const int t = blockIdx.x * 256 + threadIdx.x;
  const int i = t * 4;
  if (i < 3 * NW) {
    const float* s; int off;
    if (i < NW)          { s = Wq; off = i; }
    else if (i < 2 * NW) { s = Wk; off = i - NW; }
    else                 { s = Wv; off = i - 2 * NW; }
    float4 v = *(const float4*)(s + off);
    bf16x4 o;
    o[0] = (bf16_t)v.x; o[1] = (bf16_t)v.y; o[2] = (bf16_t)v.z; o[3] = (bf16_t)v.w;
    *(bf16x4*)(wqkv + i) = o;
  } else if (i < 4 * NW) {
    const int off = i - 3 * NW;
    float4 v = *(const float4*)(Wo + off);
    bf16x4 o;
    o[0] = (bf16_t)v.x; o[1] = (bf16_t)v.y; o[2] = (bf16_t)v.z; o[3] = (bf16_t)v.w;
    *(bf16x4*)(wob + off) = o;
  }
  if (t < 2304) qkvb[t] = t < 768 ? bq[t] : (t < 1536 ? bk[t - 768] : bv[t - 1536]);
}

// ---------------- fused QKV GEMM: 256x128 tile, 512 thr = 8 waves (2M x 2N x ... ) ----------------
// Per k-step stages 48KB (A 256x64 + B 128x64) feeding 2x the MFMA of the 128-tile:
// compute:staged-byte +33%, W-panel re-reads halved. LDS 48KB -> 3 blocks/CU (24 waves).
// Staging decode (R9-derivation, coverage checked): A rows w*32+i*8+lr8 (i<4) = 0..255
// once; B rows w*16+i*8+lr8 (i<2) = 0..127 once; chunk-XOR swizzle invariant to row+128.
// Region branch hoisted outside K-loop (R17 VGPR lesson). XCD bm-affinity: 576 = 8x(4x18).
__global__ __launch_bounds__(512) void gemm_qkv(
    const bf16_t* __restrict__ A, const bf16_t* __restrict__ B,
    const float* __restrict__ bias,
    bf16_t* __restrict__ qb, bf16_t* __restrict__ kb2, bf16_t* __restrict__ vtb) {
  __shared__ __align__(16) bf16_t As[256 * 64];
  __shared__ __align__(16) bf16_t Bs[128 * 64];
  const int K = 768;
  const int p = blockIdx.x;
  const int xcd = p & 7, u = p >> 3;           // u in 0..71
  const int bm = xcd * 4 + u / 18;             // 4 bm rows (256 t each) per XCD
  const int bn = u - (u / 18) * 18;            // bn fastest within a bm
  const int tid = threadIdx.x;
  const int w = tid >> 6, l = tid & 63, lg = l >> 4, ln = l & 15;
  const int wr = w >> 1, wc = w & 1;           // wr 0..3 (A 64-row strip), wc 0..1 (B 64-col strip)
  const int lr8 = l >> 3, lc8 = l & 7;
  const int region = (bn * 128) / 768;
  const int ln7 = ln & 7;
  f32x4 acc[4][4] = {};
  if (region != 2) {  // ---- q/k path ----
    for (int kb = 0; kb < K / 64; ++kb) {
      const int k0 = kb * 64;
#pragma unroll
      for (int i = 0; i < 4; ++i) {            // A: 256 rows, 8 chunks/row
        const int row = w * 32 + i * 8 + lr8;
        const int so = k0 + ((lc8 ^ (row & 7)) << 3);
        gld_lds16(A + (size_t)(bm * 256 + row) * K + so, As + (w * 32 + i * 8) * 64 + l * 8);
      }
#pragma unroll
      for (int i = 0; i < 2; ++i) {            // B: 128 rows
        const int row = w * 16 + i * 8 + lr8;
        const int so = k0 + ((lc8 ^ (row & 7)) << 3);
        gld_lds16(B + (size_t)(bn * 128 + row) * K + so, Bs + (w * 16 + i * 8) * 64 + l * 8);
      }
      __syncthreads();
#pragma unroll
      for (int kk = 0; kk < 2; ++kk) {
        bf16x8 af[4], bfr[4];
#pragma unroll
        for (int m = 0; m < 4; ++m) {
          const int jc = ((kk * 4 + lg) ^ ln7) << 3;
          af[m]  = *(const bf16x8*)(As + (wr * 64 + m * 16 + ln) * 64 + jc);
          bfr[m] = *(const bf16x8*)(Bs + (wc * 64 + m * 16 + ln) * 64 + jc);
        }
#pragma unroll
        for (int m = 0; m < 4; ++m)
#pragma unroll
          for (int n = 0; n < 4; ++n) acc[m][n] = MFMA16(af[m], bfr[n], acc[m][n]);
      }
      __syncthreads();
    }
    const float scl = (region == 0) ? 0.18033688011112042f : 1.0f;  // 0.125*log2(e)
    bf16_t* dst = region == 0 ? qb : kb2;
#pragma unroll
    for (int m = 0; m < 4; ++m)
#pragma unroll
      for (int n = 0; n < 4; ++n)
#pragma unroll
        for (int j = 0; j < 4; ++j) {
          const int gm = bm * 256 + wr * 64 + m * 16 + lg * 4 + j;   // t
          const int gn = bn * 128 + wc * 64 + n * 16 + ln;           // qkv col
          const float v = (acc[m][n][j] + bias[gn]) * scl;
          const int c = gn - region * 768;
          const int bb = gm >> 12, tt = gm & 4095;
          const int hh = c >> 6, d = c & 63;
          dst[((size_t)(bb * 12 + hh) * 4096 + tt) * 64 + d] = (bf16_t)v;
        }
  } else {  // ---- v path: C^T (swapped operands) for coalesced [B,H,D,T] writes ----
    for (int kb = 0; kb < K / 64; ++kb) {
      const int k0 = kb * 64;
#pragma unroll
      for (int i = 0; i < 4; ++i) {
        const int row = w * 32 + i * 8 + lr8;
        const int so = k0 + ((lc8 ^ (row & 7)) << 3);
        gld_lds16(A + (size_t)(bm * 256 + row) * K + so, As + (w * 32 + i * 8) * 64 + l * 8);
      }
#pragma unroll
      for (int i = 0; i < 2; ++i) {
        const int row = w * 16 + i * 8 + lr8;
        const int so = k0 + ((lc8 ^ (row & 7)) << 3);
        gld_lds16(B + (size_t)(bn * 128 + row) * K + so, Bs + (w * 16 + i * 8) * 64 + l * 8);
      }
      __syncthreads();
#pragma unroll
      for (int kk = 0; kk < 2; ++kk) {
        bf16x8 af[4], bfr[4];
#pragma unroll
        for (int m = 0; m < 4; ++m) {
          const int jc = ((kk * 4 + lg) ^ ln7) << 3;
          af[m]  = *(const bf16x8*)(As + (wr * 64 + m * 16 + ln) * 64 + jc);
          bfr[m] = *(const bf16x8*)(Bs + (wc * 64 + m * 16 + ln) * 64 + jc);
        }
#pragma unroll
        for (int m = 0; m < 4; ++m)
#pragma unroll
          for (int n = 0; n < 4; ++n) acc[m][n] = MFMA16(bfr[n], af[m], acc[m][n]);
      }
      __syncthreads();
    }
#pragma unroll
    for (int m = 0; m < 4; ++m)
#pragma unroll
      for (int n = 0; n < 4; ++n)
#pragma unroll
        for (int j = 0; j < 4; ++j) {
          const int gn = bn * 128 + wc * 64 + n * 16 + lg * 4 + j;   // qkv col (channel)
          const int gm = bm * 256 + wr * 64 + m * 16 + ln;           // t
          const float v = acc[m][n][j] + bias[gn];
          const int c = gn - 1536;
          const int bb = gm >> 12, tt = gm & 4095;
          const int hh = c >> 6, d = c & 63;
          vtb[((size_t)(bb * 12 + hh) * 64 + d) * 4096 + tt] = (bf16_t)v;
        }
  }
}

// ---------------- flash attention (R17-verified, 73.7us): shared-tile k-split, 32KB LDS ----------------
__global__ __launch_bounds__(512) void attn_fwd(
    const bf16_t* __restrict__ q, const bf16_t* __restrict__ k,
    const bf16_t* __restrict__ vt, bf16_t* __restrict__ y) {
  __shared__ __align__(16) unsigned char SMEM[33280];
  bf16_t* Ks = (bf16_t*)SMEM;            // [dbuf][4096] (8KB per buf)
  bf16_t* Vs = (bf16_t*)(SMEM + 16384);  // [dbuf][4096]
  float*  osh = (float*)SMEM;            // combine: [4][32][64] f32 (32KB)
  float*  lsh = (float*)(SMEM + 32768);  // combine: [4][32] f32 row sums

  const int p = blockIdx.x;
  const int xcd = p & 7, slot = p >> 3;        // 96 slots per XCD
  const int hb = xcd + 8 * (slot % 3);         // 3 heads per XCD (L2-resident K/V)
  const int qt = 31 - slot / 3;                // heavy-first
  const int tid = threadIdx.x;
  const int w = tid >> 6, l = tid & 63, lq = l & 31, lh = l >> 5;
  const int wq = w >> 1, wc = w & 1;
  const size_t hbo = (size_t)hb * (4096 * 64);
  const bf16_t* qh = q + hbo;
  const bf16_t* kh = k + hbo;
  const bf16_t* vh = vt + hbo;

  const int q0 = qt * 128 + wq * 32;           // wave's first q row
  const int qidx = q0 + lq;                    // this lane's q row
  const int nst = 2 * qt + 2;                  // tiles to sweep (each once)

  const int sr = ((tid >> 8) << 5) | (tid & 31);
  const int sc = ((((tid >> 6) & 3) << 1) | ((tid >> 5) & 1)) << 3;
  const bf16_t* ksrc = kh + ((size_t)sr * 64 + sc);
  const bf16_t* vsrc = vh + ((size_t)sr * 4096 + sc);

  bf16x8 qf[4];
#pragma unroll
  for (int ds = 0; ds < 4; ++ds)
    qf[ds] = *(const bf16x8*)(qh + (size_t)qidx * 64 + 16 * ds + 8 * lh);
  bf16x8 ones;
#pragma unroll
  for (int j = 0; j < 8; ++j) ones[j] = (bf16_t)1.0f;

  gld_lds16(ksrc, Ks + tid * 8);
  gld_lds16(vsrc, Vs + tid * 8);
  __syncthreads();

  f32x16 o0 = {}, o1 = {}, osum = {};

  int cur = 0;
  for (int t = 0; t < nst; ++t) {
    if (t + 1 < nst) {  // prefetch next tile into other buffer
      gld_lds16(ksrc + 4096, Ks + (cur ^ 1) * 4096 + tid * 8);
      gld_lds16(vsrc + 64, Vs + (cur ^ 1) * 4096 + tid * 8);
    }
    ksrc += 4096; vsrc += 64;
    const int kvb = t * 64;
    if (kvb <= q0 + 31) {  // causal: this wave still needs this tile
      const bool diag = (kvb + 63 > q0);
      const bf16_t* KsW = Ks + cur * 4096;
      const bf16_t* VsW = Vs + cur * 4096;
      f32x16 st = {};
      __builtin_amdgcn_s_setprio(1);
#pragma unroll
      for (int ds = 0; ds < 4; ++ds) {
        bf16x8 kf = *(const bf16x8*)(KsW + (wc * 4 + ds) * 512 + l * 8);
        st = MFMA32(kf, qf[ds], st);
      }
      __builtin_amdgcn_s_setprio(0);
      float pv[16];
#pragma unroll
      for (int r = 0; r < 16; ++r) pv[r] = __builtin_amdgcn_exp2f(st[r]);
      if (diag) {
        const int kb0 = kvb + wc * 32 + 4 * lh;
#pragma unroll
        for (int r = 0; r < 16; ++r)
          if (kb0 + (r & 3) + 8 * (r >> 2) > qidx) pv[r] = 0.f;
      }
      u32 pq[8];
#pragma unroll
      for (int g = 0; g < 8; ++g) pq[g] = cvt_pk_bf16(pv[2 * g], pv[2 * g + 1]);
#pragma unroll
      for (int ks2 = 0; ks2 < 2; ++ks2) {
        asm("v_permlane32_swap_b32 %0, %1" : "+v"(pq[4 * ks2 + 0]), "+v"(pq[4 * ks2 + 2]));
        asm("v_permlane32_swap_b32 %0, %1" : "+v"(pq[4 * ks2 + 1]), "+v"(pq[4 * ks2 + 3]));
      }
      __builtin_amdgcn_s_setprio(1);
#pragma unroll
      for (int ks = 0; ks < 2; ++ks) {
        bf16x8 pa = *(const bf16x8*)&pq[ks * 4];
        bf16x8 v0 = *(const bf16x8*)(VsW + (2 * wc + ks) * 512 + l * 8);
        bf16x8 v1 = *(const bf16x8*)(VsW + (4 + 2 * wc + ks) * 512 + l * 8);
        o0 = MFMA32(pa, v0, o0);
        o1 = MFMA32(pa, v1, o1);
        osum = MFMA32(pa, ones, osum);   // row-sums of P on the MFMA pipe
      }
      __builtin_amdgcn_s_setprio(0);
    }
    __syncthreads();
    cur ^= 1;
  }

  if (wc == 1) {
#pragma unroll
    for (int r = 0; r < 16; ++r) {
      osh[wq * 2048 + r * 64 + l] = o0[r];
      osh[wq * 2048 + (16 + r) * 64 + l] = o1[r];
    }
    if (lq == 0) {
#pragma unroll
      for (int r = 0; r < 16; ++r)
        lsh[wq * 32 + (r & 3) + 8 * (r >> 2) + 4 * lh] = osum[r];
    }
  }
  __syncthreads();
  if (wc == 0) {
#pragma unroll
    for (int r = 0; r < 16; ++r) {
      o0[r] += osh[wq * 2048 + r * 64 + l];
      o1[r] += osh[wq * 2048 + (16 + r) * 64 + l];
    }
    float linv[16];
#pragma unroll
    for (int r = 0; r < 16; ++r) {
      const int rl = (r & 3) + 8 * (r >> 2) + 4 * lh;
      linv[r] = 1.0f / (osum[r] + lsh[wq * 32 + rl]);
    }
    const int b = hb / 12, h = hb - b * 12;
#pragma unroll
    for (int r = 0; r < 16; ++r) {
      const int row = q0 + (r & 3) + 8 * (r >> 2) + 4 * lh;
      bf16_t* yr = y + ((size_t)b * 4096 + row) * 768 + h * 64 + lq;
      yr[0]  = (bf16_t)(o0[r] * linv[r]);
      yr[32] = (bf16_t)(o1[r] * linv[r]);
    }
  }
}

// ---------------- output GEMM (R17-verified): 64x128 tile, grid 768 = 3/CU ----------------
__global__ __launch_bounds__(256) void gemm_out(
    const bf16_t* __restrict__ A, const bf16_t* __restrict__ B,
    const float* __restrict__ bias, float* __restrict__ out) {
  __shared__ __align__(16) bf16_t As[64 * 64];
  __shared__ __align__(16) bf16_t Bs[128 * 64];
  const int K = 768;
  const int p = blockIdx.x;
  const int xcd = p & 7, u = p >> 3;           // u in 0..95
  const int bm = xcd * 16 + u / 6;             // 16 bm rows per XCD (128 total)
  const int bn = u - (u / 6) * 6;
  const int tid = threadIdx.x;
  const int w = tid >> 6, l = tid & 63, lg = l >> 4, ln = l & 15;
  const int lr8 = l >> 3, lc8 = l & 7;
  const int ln7 = ln & 7;
  f32x4 acc[4][2] = {};
  for (int kb = 0; kb < K / 64; ++kb) {
    const int k0 = kb * 64;
#pragma unroll
    for (int i = 0; i < 2; ++i) {              // A: 64 rows, 2 chunk-passes
      const int row = w * 16 + i * 8 + lr8;
      const int so = k0 + ((lc8 ^ (row & 7)) << 3);
      gld_lds16(A + (size_t)(bm * 64 + row) * K + so, As + (w * 16 + i * 8) * 64 + l * 8);
    }
#pragma unroll
    for (int i = 0; i < 4; ++i) {              // B: 128 rows, 4 chunk-passes
      const int row = w * 32 + i * 8 + lr8;
      const int so = k0 + ((lc8 ^ (row & 7)) << 3);
      gld_lds16(B + (size_t)(bn * 128 + row) * K + so, Bs + (w * 32 + i * 8) * 64 + l * 8);
    }
    __syncthreads();
#pragma unroll
    for (int kk = 0; kk < 2; ++kk) {
      const int jc = ((kk * 4 + lg) ^ ln7) << 3;
      bf16x8 af[4], bfr[2];
#pragma unroll
      for (int m = 0; m < 4; ++m)
        af[m] = *(const bf16x8*)(As + (m * 16 + ln) * 64 + jc);
#pragma unroll
      for (int n = 0; n < 2; ++n)
        bfr[n] = *(const bf16x8*)(Bs + (w * 32 + n * 16 + ln) * 64 + jc);
#pragma unroll
      for (int m = 0; m < 4; ++m)
#pragma unroll
        for (int n = 0; n < 2; ++n) acc[m][n] = MFMA16(af[m], bfr[n], acc[m][n]);
    }
    __syncthreads();
  }
#pragma unroll
  for (int m = 0; m < 4; ++m) {
#pragma unroll
    for (int n = 0; n < 2; ++n) {
#pragma unroll
      for (int j = 0; j < 4; ++j) {
        const int gm = bm * 64 + m * 16 + lg * 4 + j;
        const int gn = bn * 128 + w * 32 + n * 16 + ln;
        out[(size_t)gm * 768 + gn] = acc[m][n][j] + bias[gn];
      }
    }
  }
}

// ---------------- launch ----------------
extern "C" void kernel_launch(void* const* d_in, const int* in_sizes, int n_in,
                              void* d_out, int out_size, void* d_ws, size_t ws_size,
                              hipStream_t stream) {
  const float* x  = (const float*)d_in[0];
  const float* Wq = (const float*)d_in[1];
  const float* bq = (const float*)d_in[2];
  const float* Wk = (const float*)d_in[3];
  const float* bk = (const float*)d_in[4];
  const float* Wv = (const float*)d_in[5];
  const float* bv = (const float*)d_in[6];
  const float* Wo = (const float*)d_in[7];
  const float* bo = (const float*)d_in[8];
  float* out = (float*)d_out;

  const int M = 8192, C = 768, QKV = 2304;
  bf16_t* xb   = (bf16_t*)d_ws;                    // [8192][768]
  bf16_t* wqkv = xb + (size_t)M * C;               // [2304][768]
  bf16_t* wob  = wqkv + (size_t)QKV * C;           // [768][768]
  float*  qkvb = (float*)(wob + (size_t)C * C);    // [2304]
  bf16_t* qbuf = (bf16_t*)(qkvb + QKV);            // [B,H,T,D] (q pre-scaled)
  bf16_t* kbuf = qbuf + (size_t)M * C;             // [B,H,T,D]
  bf16_t* vtb  = kbuf + (size_t)M * C;             // [B,H,D,T]
  bf16_t* yb   = xb;                               // reuse xb (dead after gemm_qkv)

  cast_f32_bf16<<<6144, 256, 0, stream>>>(x, xb, M * C);
  prep_w<<<2304, 256, 0, stream>>>(Wq, Wk, Wv, Wo, bq, bk, bv, wqkv, wob, qkvb);

  gemm_qkv<<<576, 512, 0, stream>>>(xb, wqkv, qkvb, qbuf, kbuf, vtb);
  attn_fwd<<<768, 512, 0, stream>>>(qbuf, kbuf, vtb, yb);
  gemm_out<<<768, 256, 0, stream>>>(yb, wob, bo, out);
}

// Round 20
// 150.749 us; speedup vs baseline: 1.2229x; 1.0398x over previous
//
#include <hip/hip_runtime.h>

typedef __bf16 bf16_t;
typedef __bf16 bf16x4 __attribute__((ext_vector_type(4)));
typedef __bf16 bf16x8 __attribute__((ext_vector_type(8)));
typedef float  f32x4  __attribute__((ext_vector_type(4)));
typedef float  f32x16 __attribute__((ext_vector_type(16)));
typedef unsigned int u32;

#define MFMA16(a, b, c) __builtin_amdgcn_mfma_f32_16x16x32_bf16((a), (b), (c), 0, 0, 0)
#define MFMA32(a, b, c) __builtin_amdgcn_mfma_f32_32x32x16_bf16((a), (b), (c), 0, 0, 0)

__device__ __forceinline__ void gld_lds16(const bf16_t* g, bf16_t* l) {
  __builtin_amdgcn_global_load_lds((__attribute__((address_space(1))) void*)g,
                                   (__attribute__((address_space(3))) void*)l, 16, 0, 0);
}
__device__ __forceinline__ u32 cvt_pk_bf16(float lo, float hi) {
  u32 r;
  asm("v_cvt_pk_bf16_f32 %0, %1, %2" : "=v"(r) : "v"(lo), "v"(hi));
  return r;
}

// ---------------- prep: x cast (big) ----------------
__global__ void cast_f32_bf16(const float* __restrict__ s, bf16_t* __restrict__ d, int n) {
  int i = (blockIdx.x * blockDim.x + threadIdx.x) * 4;
  if (i >= n) return;
  float4 v = *(const float4*)(s + i);
  bf16x4 o;
  o[0] = (bf16_t)v.x; o[1] = (bf16_t)v.y; o[2] = (bf16_t)v.z; o[3] = (bf16_t)v.w;
  *(bf16x4*)(d + i) = o;
}

// ---------------- prep: all weight casts + bias concat in one launch ----------------
__global__ void prep_w(const float* __restrict__ Wq, const float* __restrict__ Wk,
                       const float* __restrict__ Wv, const float* __restrict__ Wo,
                       const float* __restrict__ bq, const float* __restrict__ bk,
                       const float* __restrict__ bv,
                       bf16_t* __restrict__ wqkv, bf16_t* __restrict__ wob,
                       float* __restrict__ qkvb) {
  const int NW = 768 * 768;
  const int t = blockIdx.x * 256 + threadIdx.x;
  const int i = t * 4;
  if (i < 3 * NW) {
    const float* s; int off;
    if (i < NW)          { s = Wq; off = i; }
    else if (i < 2 * NW) { s = Wk; off = i - NW; }
    else                 { s = Wv; off = i - 2 * NW; }
    float4 v = *(const float4*)(s + off);
    bf16x4 o;
    o[0] = (bf16_t)v.x; o[1] = (bf16_t)v.y; o[2] = (bf16_t)v.z; o[3] = (bf16_t)v.w;
    *(bf16x4*)(wqkv + i) = o;
  } else if (i < 4 * NW) {
    const int off = i - 3 * NW;
    float4 v = *(const float4*)(Wo + off);
    bf16x4 o;
    o[0] = (bf16_t)v.x; o[1] = (bf16_t)v.y; o[2] = (bf16_t)v.z; o[3] = (bf16_t)v.w;
    *(bf16x4*)(wob + off) = o;
  }
  if (t < 2304) qkvb[t] = t < 768 ? bq[t] : (t < 1536 ? bk[t - 768] : bv[t - 1536]);
}

// ---------------- fused QKV GEMM (R17-verified): 128x128, region branch hoisted ----------------
__global__ __launch_bounds__(256) void gemm_qkv(
    const bf16_t* __restrict__ A, const bf16_t* __restrict__ B,
    const float* __restrict__ bias,
    bf16_t* __restrict__ qb, bf16_t* __restrict__ kb2, bf16_t* __restrict__ vtb) {
  __shared__ __align__(16) bf16_t As[128 * 64];
  __shared__ __align__(16) bf16_t Bs[128 * 64];
  const int K = 768;
  const int p = blockIdx.x;
  const int xcd = p & 7, u = p >> 3;           // u in 0..143
  const int bm = xcd * 8 + u / 18;             // 8 bm rows per XCD
  const int bn = u - (u / 18) * 18;            // bn fastest within a bm
  const int tid = threadIdx.x;
  const int w = tid >> 6, l = tid & 63, lg = l >> 4, ln = l & 15;
  const int wr = w >> 1, wc = w & 1;
  const int lr8 = l >> 3, lc8 = l & 7;
  const int region = (bn * 128) / 768;
  const int ln7 = ln & 7;
  f32x4 acc[4][4] = {};
  if (region != 2) {  // ---- q/k path: normal operand order ----
    for (int kb = 0; kb < K / 64; ++kb) {
      const int k0 = kb * 64;
#pragma unroll
      for (int i = 0; i < 4; ++i) {
        const int row = w * 32 + i * 8 + lr8;
        const int so = k0 + ((lc8 ^ (row & 7)) << 3);
        gld_lds16(A + (size_t)(bm * 128 + row) * K + so, As + (w * 32 + i * 8) * 64 + l * 8);
        gld_lds16(B + (size_t)(bn * 128 + row) * K + so, Bs + (w * 32 + i * 8) * 64 + l * 8);
      }
      __syncthreads();
#pragma unroll
      for (int kk = 0; kk < 2; ++kk) {
        bf16x8 af[4], bfr[4];
#pragma unroll
        for (int m = 0; m < 4; ++m) {
          const int jc = ((kk * 4 + lg) ^ ln7) << 3;
          af[m]  = *(const bf16x8*)(As + (wr * 64 + m * 16 + ln) * 64 + jc);
          bfr[m] = *(const bf16x8*)(Bs + (wc * 64 + m * 16 + ln) * 64 + jc);
        }
#pragma unroll
        for (int m = 0; m < 4; ++m)
#pragma unroll
          for (int n = 0; n < 4; ++n) acc[m][n] = MFMA16(af[m], bfr[n], acc[m][n]);
      }
      __syncthreads();
    }
    const float scl = (region == 0) ? 0.18033688011112042f : 1.0f;  // 0.125*log2(e)
    bf16_t* dst = region == 0 ? qb : kb2;
#pragma unroll
    for (int m = 0; m < 4; ++m)
#pragma unroll
      for (int n = 0; n < 4; ++n)
#pragma unroll
        for (int j = 0; j < 4; ++j) {
          const int gm = bm * 128 + wr * 64 + m * 16 + lg * 4 + j;   // t
          const int gn = bn * 128 + wc * 64 + n * 16 + ln;           // qkv col
          const float v = (acc[m][n][j] + bias[gn]) * scl;
          const int c = gn - region * 768;
          const int bb = gm >> 12, tt = gm & 4095;
          const int hh = c >> 6, d = c & 63;
          dst[((size_t)(bb * 12 + hh) * 4096 + tt) * 64 + d] = (bf16_t)v;
        }
  } else {  // ---- v path: C^T (swapped operands) for coalesced [B,H,D,T] writes ----
    for (int kb = 0; kb < K / 64; ++kb) {
      const int k0 = kb * 64;
#pragma unroll
      for (int i = 0; i < 4; ++i) {
        const int row = w * 32 + i * 8 + lr8;
        const int so = k0 + ((lc8 ^ (row & 7)) << 3);
        gld_lds16(A + (size_t)(bm * 128 + row) * K + so, As + (w * 32 + i * 8) * 64 + l * 8);
        gld_lds16(B + (size_t)(bn * 128 + row) * K + so, Bs + (w * 32 + i * 8) * 64 + l * 8);
      }
      __syncthreads();
#pragma unroll
      for (int kk = 0; kk < 2; ++kk) {
        bf16x8 af[4], bfr[4];
#pragma unroll
        for (int m = 0; m < 4; ++m) {
          const int jc = ((kk * 4 + lg) ^ ln7) << 3;
          af[m]  = *(const bf16x8*)(As + (wr * 64 + m * 16 + ln) * 64 + jc);
          bfr[m] = *(const bf16x8*)(Bs + (wc * 64 + m * 16 + ln) * 64 + jc);
        }
#pragma unroll
        for (int m = 0; m < 4; ++m)
#pragma unroll
          for (int n = 0; n < 4; ++n) acc[m][n] = MFMA16(bfr[n], af[m], acc[m][n]);
      }
      __syncthreads();
    }
#pragma unroll
    for (int m = 0; m < 4; ++m)
#pragma unroll
      for (int n = 0; n < 4; ++n)
#pragma unroll
        for (int j = 0; j < 4; ++j) {
          const int gn = bn * 128 + wc * 64 + n * 16 + lg * 4 + j;   // qkv col (channel)
          const int gm = bm * 128 + wr * 64 + m * 16 + ln;           // t
          const float v = acc[m][n][j] + bias[gn];
          const int c = gn - 1536;
          const int bb = gm >> 12, tt = gm & 4095;
          const int hh = c >> 6, d = c & 63;
          vtb[((size_t)(bb * 12 + hh) * 64 + d) * 4096 + tt] = (bf16_t)v;
        }
  }
}

// ---------------- flash attention (R17-verified, 73.7us): shared-tile k-split, 32KB LDS ----------------
__global__ __launch_bounds__(512) void attn_fwd(
    const bf16_t* __restrict__ q, const bf16_t* __restrict__ k,
    const bf16_t* __restrict__ vt, bf16_t* __restrict__ y) {
  __shared__ __align__(16) unsigned char SMEM[33280];
  bf16_t* Ks = (bf16_t*)SMEM;            // [dbuf][4096] (8KB per buf)
  bf16_t* Vs = (bf16_t*)(SMEM + 16384);  // [dbuf][4096]
  float*  osh = (float*)SMEM;            // combine: [4][32][64] f32 (32KB)
  float*  lsh = (float*)(SMEM + 32768);  // combine: [4][32] f32 row sums

  const int p = blockIdx.x;
  const int xcd = p & 7, slot = p >> 3;        // 96 slots per XCD
  const int hb = xcd + 8 * (slot % 3);         // 3 heads per XCD (L2-resident K/V)
  const int qt = 31 - slot / 3;                // heavy-first
  const int tid = threadIdx.x;
  const int w = tid >> 6, l = tid & 63, lq = l & 31, lh = l >> 5;
  const int wq = w >> 1, wc = w & 1;
  const size_t hbo = (size_t)hb * (4096 * 64);
  const bf16_t* qh = q + hbo;
  const bf16_t* kh = k + hbo;
  const bf16_t* vh = vt + hbo;

  const int q0 = qt * 128 + wq * 32;           // wave's first q row
  const int qidx = q0 + lq;                    // this lane's q row
  const int nst = 2 * qt + 2;                  // tiles to sweep (each once)

  const int sr = ((tid >> 8) << 5) | (tid & 31);
  const int sc = ((((tid >> 6) & 3) << 1) | ((tid >> 5) & 1)) << 3;
  const bf16_t* ksrc = kh + ((size_t)sr * 64 + sc);
  const bf16_t* vsrc = vh + ((size_t)sr * 4096 + sc);

  bf16x8 qf[4];
#pragma unroll
  for (int ds = 0; ds < 4; ++ds)
    qf[ds] = *(const bf16x8*)(qh + (size_t)qidx * 64 + 16 * ds + 8 * lh);
  bf16x8 ones;
#pragma unroll
  for (int j = 0; j < 8; ++j) ones[j] = (bf16_t)1.0f;

  gld_lds16(ksrc, Ks + tid * 8);
  gld_lds16(vsrc, Vs + tid * 8);
  __syncthreads();

  f32x16 o0 = {}, o1 = {}, osum = {};

  int cur = 0;
  for (int t = 0; t < nst; ++t) {
    if (t + 1 < nst) {  // prefetch next tile into other buffer
      gld_lds16(ksrc + 4096, Ks + (cur ^ 1) * 4096 + tid * 8);
      gld_lds16(vsrc + 64, Vs + (cur ^ 1) * 4096 + tid * 8);
    }
    ksrc += 4096; vsrc += 64;
    const int kvb = t * 64;
    if (kvb <= q0 + 31) {  // causal: this wave still needs this tile
      const bool diag = (kvb + 63 > q0);
      const bf16_t* KsW = Ks + cur * 4096;
      const bf16_t* VsW = Vs + cur * 4096;
      f32x16 st = {};
      __builtin_amdgcn_s_setprio(1);
#pragma unroll
      for (int ds = 0; ds < 4; ++ds) {
        bf16x8 kf = *(const bf16x8*)(KsW + (wc * 4 + ds) * 512 + l * 8);
        st = MFMA32(kf, qf[ds], st);
      }
      __builtin_amdgcn_s_setprio(0);
      float pv[16];
#pragma unroll
      for (int r = 0; r < 16; ++r) pv[r] = __builtin_amdgcn_exp2f(st[r]);
      if (diag) {
        const int kb0 = kvb + wc * 32 + 4 * lh;
#pragma unroll
        for (int r = 0; r < 16; ++r)
          if (kb0 + (r & 3) + 8 * (r >> 2) > qidx) pv[r] = 0.f;
      }
      u32 pq[8];
#pragma unroll
      for (int g = 0; g < 8; ++g) pq[g] = cvt_pk_bf16(pv[2 * g], pv[2 * g + 1]);
#pragma unroll
      for (int ks2 = 0; ks2 < 2; ++ks2) {
        asm("v_permlane32_swap_b32 %0, %1" : "+v"(pq[4 * ks2 + 0]), "+v"(pq[4 * ks2 + 2]));
        asm("v_permlane32_swap_b32 %0, %1" : "+v"(pq[4 * ks2 + 1]), "+v"(pq[4 * ks2 + 3]));
      }
      __builtin_amdgcn_s_setprio(1);
#pragma unroll
      for (int ks = 0; ks < 2; ++ks) {
        bf16x8 pa = *(const bf16x8*)&pq[ks * 4];
        bf16x8 v0 = *(const bf16x8*)(VsW + (2 * wc + ks) * 512 + l * 8);
        bf16x8 v1 = *(const bf16x8*)(VsW + (4 + 2 * wc + ks) * 512 + l * 8);
        o0 = MFMA32(pa, v0, o0);
        o1 = MFMA32(pa, v1, o1);
        osum = MFMA32(pa, ones, osum);   // row-sums of P on the MFMA pipe
      }
      __builtin_amdgcn_s_setprio(0);
    }
    __syncthreads();
    cur ^= 1;
  }

  if (wc == 1) {
#pragma unroll
    for (int r = 0; r < 16; ++r) {
      osh[wq * 2048 + r * 64 + l] = o0[r];
      osh[wq * 2048 + (16 + r) * 64 + l] = o1[r];
    }
    if (lq == 0) {
#pragma unroll
      for (int r = 0; r < 16; ++r)
        lsh[wq * 32 + (r & 3) + 8 * (r >> 2) + 4 * lh] = osum[r];
    }
  }
  __syncthreads();
  if (wc == 0) {
#pragma unroll
    for (int r = 0; r < 16; ++r) {
      o0[r] += osh[wq * 2048 + r * 64 + l];
      o1[r] += osh[wq * 2048 + (16 + r) * 64 + l];
    }
    float linv[16];
#pragma unroll
    for (int r = 0; r < 16; ++r) {
      const int rl = (r & 3) + 8 * (r >> 2) + 4 * lh;
      linv[r] = 1.0f / (osum[r] + lsh[wq * 32 + rl]);
    }
    const int b = hb / 12, h = hb - b * 12;
#pragma unroll
    for (int r = 0; r < 16; ++r) {
      const int row = q0 + (r & 3) + 8 * (r >> 2) + 4 * lh;
      bf16_t* yr = y + ((size_t)b * 4096 + row) * 768 + h * 64 + lq;
      yr[0]  = (bf16_t)(o0[r] * linv[r]);
      yr[32] = (bf16_t)(o1[r] * linv[r]);
    }
  }
}

// ---------------- output GEMM (R17-verified): 64x128 tile, grid 768 = 3/CU ----------------
__global__ __launch_bounds__(256) void gemm_out(
    const bf16_t* __restrict__ A, const bf16_t* __restrict__ B,
    const float* __restrict__ bias, float* __restrict__ out) {
  __shared__ __align__(16) bf16_t As[64 * 64];
  __shared__ __align__(16) bf16_t Bs[128 * 64];
  const int K = 768;
  const int p = blockIdx.x;
  const int xcd = p & 7, u = p >> 3;           // u in 0..95
  const int bm = xcd * 16 + u / 6;             // 16 bm rows per XCD (128 total)
  const int bn = u - (u / 6) * 6;
  const int tid = threadIdx.x;
  const int w = tid >> 6, l = tid & 63, lg = l >> 4, ln = l & 15;
  const int lr8 = l >> 3, lc8 = l & 7;
  const int ln7 = ln & 7;
  f32x4 acc[4][2] = {};
  for (int kb = 0; kb < K / 64; ++kb) {
    const int k0 = kb * 64;
#pragma unroll
    for (int i = 0; i < 2; ++i) {              // A: 64 rows, 2 chunk-passes
      const int row = w * 16 + i * 8 + lr8;
      const int so = k0 + ((lc8 ^ (row & 7)) << 3);
      gld_lds16(A + (size_t)(bm * 64 + row) * K + so, As + (w * 16 + i * 8) * 64 + l * 8);
    }
#pragma unroll
    for (int i = 0; i < 4; ++i) {              // B: 128 rows, 4 chunk-passes
      const int row = w * 32 + i * 8 + lr8;
      const int so = k0 + ((lc8 ^ (row & 7)) << 3);
      gld_lds16(B + (size_t)(bn * 128 + row) * K + so, Bs + (w * 32 + i * 8) * 64 + l * 8);
    }
    __syncthreads();
#pragma unroll
    for (int kk = 0; kk < 2; ++kk) {
      const int jc = ((kk * 4 + lg) ^ ln7) << 3;
      bf16x8 af[4], bfr[2];
#pragma unroll
      for (int m = 0; m < 4; ++m)
        af[m] = *(const bf16x8*)(As + (m * 16 + ln) * 64 + jc);
#pragma unroll
      for (int n = 0; n < 2; ++n)
        bfr[n] = *(const bf16x8*)(Bs + (w * 32 + n * 16 + ln) * 64 + jc);
#pragma unroll
      for (int m = 0; m < 4; ++m)
#pragma unroll
        for (int n = 0; n < 2; ++n) acc[m][n] = MFMA16(af[m], bfr[n], acc[m][n]);
    }
    __syncthreads();
  }
#pragma unroll
  for (int m = 0; m < 4; ++m) {
#pragma unroll
    for (int n = 0; n < 2; ++n) {
#pragma unroll
      for (int j = 0; j < 4; ++j) {
        const int gm = bm * 64 + m * 16 + lg * 4 + j;
        const int gn = bn * 128 + w * 32 + n * 16 + ln;
        out[(size_t)gm * 768 + gn] = acc[m][n][j] + bias[gn];
      }
    }
  }
}

// ---------------- launch ----------------
extern "C" void kernel_launch(void* const* d_in, const int* in_sizes, int n_in,
                              void* d_out, int out_size, void* d_ws, size_t ws_size,
                              hipStream_t stream) {
  const float* x  = (const float*)d_in[0];
  const float* Wq = (const float*)d_in[1];
  const float* bq = (const float*)d_in[2];
  const float* Wk = (const float*)d_in[3];
  const float* bk = (const float*)d_in[4];
  const float* Wv = (const float*)d_in[5];
  const float* bv = (const float*)d_in[6];
  const float* Wo = (const float*)d_in[7];
  const float* bo = (const float*)d_in[8];
  float* out = (float*)d_out;

  const int M = 8192, C = 768, QKV = 2304;
  bf16_t* xb   = (bf16_t*)d_ws;                    // [8192][768]
  bf16_t* wqkv = xb + (size_t)M * C;               // [2304][768]
  bf16_t* wob  = wqkv + (size_t)QKV * C;           // [768][768]
  float*  qkvb = (float*)(wob + (size_t)C * C);    // [2304]
  bf16_t* qbuf = (bf16_t*)(qkvb + QKV);            // [B,H,T,D] (q pre-scaled)
  bf16_t* kbuf = qbuf + (size_t)M * C;             // [B,H,T,D]
  bf16_t* vtb  = kbuf + (size_t)M * C;             // [B,H,D,T]
  bf16_t* yb   = xb;                               // reuse xb (dead after gemm_qkv)

  cast_f32_bf16<<<6144, 256, 0, stream>>>(x, xb, M * C);
  prep_w<<<2304, 256, 0, stream>>>(Wq, Wk, Wv, Wo, bq, bk, bv, wqkv, wob, qkvb);

  gemm_qkv<<<1152, 256, 0, stream>>>(xb, wqkv, qkvb, qbuf, kbuf, vtb);
  attn_fwd<<<768, 512, 0, stream>>>(qbuf, kbuf, vtb, yb);
  gemm_out<<<768, 256, 0, stream>>>(yb, wob, bo, out);
}